// Round 5
// baseline (643.272 us; speedup 1.0000x reference)
//
#include <hip/hip_runtime.h>
#include <hip/hip_fp16.h>
#include <math.h>

#define N_NODES 50000
#define N_EDGES 1600000
#define EDGE_GRID 2048
#define CAP 128   // degree capacity; mean=32 (Poisson-ish), P(deg>128)~0

// atomic-free CSR build parameters
#define NB 64            // buckets per dimension (row-buckets and col-buckets)
#define BRANGE 782       // ceil(N_NODES/NB); last bucket covers 734
#define BCAP 28672       // per-bucket stream cap; expected ~25024, sigma ~157
#define BIN_BLOCKS 512
#define EPB (N_EDGES/BIN_BLOCKS)   // 3125
#define CURPAD 32        // cursor padding: 32 ints = 128 B, one line per cursor

using half8  = __attribute__((ext_vector_type(8))) _Float16;
using half4  = __attribute__((ext_vector_type(4))) _Float16;
using float4v = __attribute__((ext_vector_type(4))) float;

__device__ __forceinline__ float rl(float v, int srclane){
  return __int_as_float(__builtin_amdgcn_readlane(__float_as_int(v), srclane));
}

// ---------------- graph setup v3: fully privatized, no random global atomics ----------------
__global__ __launch_bounds__(256) void k_bin(const int* __restrict__ rowE, const int* __restrict__ colE,
                                             unsigned* __restrict__ rstream, unsigned short* __restrict__ cstream,
                                             int* __restrict__ rcur, int* __restrict__ ccur){
  __shared__ int hr[NB], hc[NB], br[NB], bc[NB];
  int t = threadIdx.x;
  if(t < NB){ hr[t] = 0; hc[t] = 0; }
  __syncthreads();
  int e0 = blockIdx.x * EPB;
  for(int e = e0 + t; e < e0 + EPB; e += 256){
    int r = __builtin_nontemporal_load(rowE + e);
    int c = __builtin_nontemporal_load(colE + e);
    atomicAdd(&hr[r/BRANGE], 1);
    atomicAdd(&hc[c/BRANGE], 1);
  }
  __syncthreads();
  if(t < NB){
    br[t] = atomicAdd(&rcur[t*CURPAD], hr[t]); hr[t] = 0;
    bc[t] = atomicAdd(&ccur[t*CURPAD], hc[t]); hc[t] = 0;
  }
  __syncthreads();
  for(int e = e0 + t; e < e0 + EPB; e += 256){
    int r = rowE[e];
    int c = colE[e];
    int rb = r/BRANGE, cb = c/BRANGE;
    int rp = br[rb] + atomicAdd(&hr[rb], 1);
    int cp = bc[cb] + atomicAdd(&hc[cb], 1);
    if(rp < BCAP) rstream[(size_t)rb*BCAP + rp] = ((unsigned)r << 16) | (unsigned)c;
    if(cp < BCAP) cstream[(size_t)cb*BCAP + cp] = (unsigned short)c;
  }
}

__global__ __launch_bounds__(256) void k_build(const unsigned* __restrict__ rstream,
                                               const unsigned short* __restrict__ cstream,
                                               const int* __restrict__ rcur, const int* __restrict__ ccur,
                                               int* __restrict__ row_fill, int* __restrict__ degcnt,
                                               unsigned short* __restrict__ csr_col){
  __shared__ int lf[BRANGE];
  int b = blockIdx.x & (NB-1);
  int role = blockIdx.x >> 6;
  int base = b*BRANGE;
  int range = min(BRANGE, N_NODES - base);
  int t = threadIdx.x;
  for(int i=t;i<range;i+=256) lf[i] = 0;
  __syncthreads();
  if(role == 0){
    int cnt = min(rcur[b*CURPAD], BCAP);
    const unsigned* sp = rstream + (size_t)b*BCAP;
    for(int i=t;i<cnt;i+=256){
      unsigned rc = sp[i];
      int r = (int)(rc >> 16), c = (int)(rc & 0xffffu);
      int pos = atomicAdd(&lf[r-base], 1);
      if(pos < CAP) csr_col[(size_t)r*CAP + pos] = (unsigned short)c;
    }
    __syncthreads();
    for(int i=t;i<range;i+=256) row_fill[base+i] = lf[i];
  } else {
    int cnt = min(ccur[b*CURPAD], BCAP);
    const unsigned short* sp = cstream + (size_t)b*BCAP;
    for(int i=t;i<cnt;i+=256){
      int c = (int)sp[i];
      atomicAdd(&lf[c-base], 1);
    }
    __syncthreads();
    for(int i=t;i<range;i+=256) degcnt[base+i] = lf[i];
  }
}

// dinv = rsqrt(deg+1); rdeg = sqrt(deg+1) overwrites degcnt; zero row N_NODES of split g tables
__global__ void k_dinv(int* __restrict__ degcnt_rdeg, float* __restrict__ dinv,
                       __half* __restrict__ gAlo, __half* __restrict__ gAhi,
                       __half* __restrict__ gBlo, __half* __restrict__ gBhi){
  int i = blockIdx.x*256 + threadIdx.x;
  if(i < N_NODES){
    float dp1 = (float)(degcnt_rdeg[i] + 1);
    dinv[i] = rsqrtf(dp1);
    ((float*)degcnt_rdeg)[i] = sqrtf(dp1);
  }
  if(i < 32){
    gAlo[(size_t)N_NODES*32 + i] = __float2half(0.f);
    gAhi[(size_t)N_NODES*32 + i] = __float2half(0.f);
    gBlo[(size_t)N_NODES*32 + i] = __float2half(0.f);
    gBhi[(size_t)N_NODES*32 + i] = __float2half(0.f);
  }
}

// ---------------- lin0: h0 = relu(x @ W_lin + b); g0 = dinv*h0 written to split tables ----------------

__global__ __launch_bounds__(256) void k_lin0(const float* __restrict__ x, const float* __restrict__ W,
                                              const float* __restrict__ b, const float* __restrict__ dinv,
                                              __half* __restrict__ h0,
                                              __half* __restrict__ gLo, __half* __restrict__ gHi){
  __shared__ float Wl[4096];
  int t = threadIdx.x;
  for(int i=t;i<4096;i+=256) Wl[i] = W[i];
  __syncthreads();
  int wave = t>>6, lane = t&63;
  int row0 = blockIdx.x*16 + wave*4;
  float4 xq = ((const float4*)(x + (size_t)row0*64))[lane];
  float a0=0,a1=0,a2=0,a3=0;
  #pragma unroll
  for(int k=0;k<64;k++){
    float w = Wl[k*64+lane];
    float comp = ((k&3)==0)?xq.x:((k&3)==1)?xq.y:((k&3)==2)?xq.z:xq.w;
    a0 += rl(comp,      (k>>2)) * w;
    a1 += rl(comp, 16 + (k>>2)) * w;
    a2 += rl(comp, 32 + (k>>2)) * w;
    a3 += rl(comp, 48 + (k>>2)) * w;
  }
  float bb = b[lane];
  float h[4] = {fmaxf(a0+bb,0.f), fmaxf(a1+bb,0.f), fmaxf(a2+bb,0.f), fmaxf(a3+bb,0.f)};
  #pragma unroll
  for(int r=0;r<4;r++){
    float dv = dinv[row0+r];
    h0[(size_t)(row0+r)*64+lane] = __float2half(h[r]);
    float gv = dv*h[r];
    if(lane < 32) gLo[(size_t)(row0+r)*32 + lane]      = __float2half(gv);
    else          gHi[(size_t)(row0+r)*32 + lane - 32] = __float2half(gv);
  }
}

// A = h @ W1[:64], B = h @ W1[64:], h reconstructed as g*rdeg from split tables
__global__ __launch_bounds__(256) void k_ab(const __half* __restrict__ gLo, const __half* __restrict__ gHi,
                                            const float* __restrict__ rdeg,
                                            const float* __restrict__ W1,
                                            __half* __restrict__ A, __half* __restrict__ B){
  __shared__ float Wa[4096];
  __shared__ float Wb[4096];
  int t = threadIdx.x;
  for(int i=t;i<4096;i+=256){ Wa[i] = W1[i]; Wb[i] = W1[4096+i]; }
  __syncthreads();
  int wave = t>>6, lane = t&63;
  int row0 = blockIdx.x*16 + wave*4;
  int l15 = lane&15;
  int myrow = row0 + (lane>>4);
  float rd = rdeg[myrow];
  const __half* gp = (l15<8) ? (gLo + (size_t)myrow*32 + 4*l15)
                             : (gHi + (size_t)myrow*32 + 4*(l15-8));
  __half2 p01 = ((const __half2*)gp)[0], p23 = ((const __half2*)gp)[1];
  float2 f01 = __half22float2(p01), f23 = __half22float2(p23);
  float4 xq = make_float4(f01.x*rd, f01.y*rd, f23.x*rd, f23.y*rd);
  float a0=0,a1=0,a2=0,a3=0,b0=0,b1=0,b2=0,b3=0;
  #pragma unroll
  for(int k=0;k<64;k++){
    float wa = Wa[k*64+lane], wb = Wb[k*64+lane];
    float comp = ((k&3)==0)?xq.x:((k&3)==1)?xq.y:((k&3)==2)?xq.z:xq.w;
    float s0 = rl(comp,      (k>>2));
    float s1 = rl(comp, 16 + (k>>2));
    float s2 = rl(comp, 32 + (k>>2));
    float s3 = rl(comp, 48 + (k>>2));
    a0 += s0*wa; a1 += s1*wa; a2 += s2*wa; a3 += s3*wa;
    b0 += s0*wb; b1 += s1*wb; b2 += s2*wb; b3 += s3*wb;
  }
  A[(size_t)(row0+0)*64+lane]=__float2half(a0); A[(size_t)(row0+1)*64+lane]=__float2half(a1);
  A[(size_t)(row0+2)*64+lane]=__float2half(a2); A[(size_t)(row0+3)*64+lane]=__float2half(a3);
  B[(size_t)(row0+0)*64+lane]=__float2half(b0); B[(size_t)(row0+1)*64+lane]=__float2half(b1);
  B[(size_t)(row0+2)*64+lane]=__float2half(b2); B[(size_t)(row0+3)*64+lane]=__float2half(b3);
}

// ---------------- GCN2 layer v12: dim-split two-pass, L2-resident 3.2MB tables ----------------
// Pass 1 (k_gather): agg[i][0:32] = sum_neigh gLo[col] + gLo[i], fp32, nt-stores.
// 8-lane groups: one instr = 8 rows x 64B. 3-step shfl_xor butterfly across groups.
__global__ __launch_bounds__(256) void k_gather(const __half* __restrict__ gT,
                          const int* __restrict__ row_fill, const unsigned short* __restrict__ csr_col,
                          float* __restrict__ agg){
  int t = threadIdx.x, wave = t>>6, lane = t&63;
  int grp = lane>>3, l8 = lane&7;
  int iw = blockIdx.x*16 + 4*wave;

  int deg[4], cv[4];
  #pragma unroll
  for(int r=0;r<4;r++) deg[r] = min(row_fill[iw+r], CAP);
  #pragma unroll
  for(int r=0;r<4;r++){
    const unsigned short* colp = csr_col + (size_t)(iw+r)*CAP;
    cv[r] = (lane < deg[r]) ? (int)__builtin_nontemporal_load(colp + lane) : 0;
  }

  for(int r=0;r<4;r++){
    const unsigned short* colp = csr_col + (size_t)(iw+r)*CAP;
    half4 selfv = *(const half4*)(gT + (size_t)(iw+r)*32 + 4*l8);
    float4v acc = {0.f,0.f,0.f,0.f};
    int base = 0;
    int cur  = cv[r];
    for(;;){
      int rem = deg[r] - base; if(rem > 64) rem = 64;
      int nit = (rem + 7) >> 3;
      int it = 0;
      for(; it+2<=nit; it+=2){
        int iA = 8*it + grp, iB = iA + 8;
        int cA = __shfl(cur, iA, 64); cA = (iA < rem) ? cA : N_NODES;
        int cB = __shfl(cur, iB, 64); cB = (iB < rem) ? cB : N_NODES;
        half4 vA = *(const half4*)(gT + (size_t)cA*32 + 4*l8);
        half4 vB = *(const half4*)(gT + (size_t)cB*32 + 4*l8);
        #pragma unroll
        for(int k=0;k<4;k++) acc[k] += (float)vA[k] + (float)vB[k];
      }
      if(it < nit){
        int iA = 8*it + grp;
        int cA = __shfl(cur, iA, 64); cA = (iA < rem) ? cA : N_NODES;
        half4 vA = *(const half4*)(gT + (size_t)cA*32 + 4*l8);
        #pragma unroll
        for(int k=0;k<4;k++) acc[k] += (float)vA[k];
      }
      base += 64;
      if(base >= deg[r]) break;
      cur = (base + lane < deg[r]) ? (int)__builtin_nontemporal_load(colp + base + lane) : 0;
    }
    #pragma unroll
    for(int k=0;k<4;k++){
      acc[k] += __shfl_xor(acc[k],  8, 64);
      acc[k] += __shfl_xor(acc[k], 16, 64);
      acc[k] += __shfl_xor(acc[k], 32, 64);
    }
    if(grp == 0){
      float4v o;
      #pragma unroll
      for(int k=0;k<4;k++) o[k] = acc[k] + (float)selfv[k];
      __builtin_nontemporal_store(o, (float4v*)(agg + (size_t)(iw+r)*32 + 4*l8));
    }
  }
}

// Pass 2 (k_gmix): gather hi-table + read agg(lo) -> mix -> MFMA (mix @ M) -> split g_out.
__global__ __launch_bounds__(256) void k_gmix(const __half* __restrict__ gT,
                          const float* __restrict__ agg, const __half* __restrict__ h0,
                          const int* __restrict__ row_fill, const unsigned short* __restrict__ csr_col,
                          const float* __restrict__ dinv,
                          const float* __restrict__ Wsl, float beta,
                          __half* __restrict__ goLo, __half* __restrict__ goHi){
  __shared__ __align__(16) _Float16 tile[16*72];
  int t = threadIdx.x, wave = t>>6, lane = t&63;
  int quad = lane>>4, l15 = lane&15;
  int grp = lane>>3, l8 = lane&7;

  half8 bfrag0, bfrag1;
  int n = 16*wave + l15;
  #pragma unroll
  for(int j=0;j<8;j++){
    int k0 = quad*8 + j;
    int k1 = 32 + quad*8 + j;
    bfrag0[j] = (_Float16)(beta*Wsl[k0*64+n] + ((k0==n)?(1.f-beta):0.f));
    bfrag1[j] = (_Float16)(beta*Wsl[k1*64+n] + ((k1==n)?(1.f-beta):0.f));
  }

  int i0 = blockIdx.x*16;
  int iw = i0 + 4*wave;

  int deg[4], cv[4];
  #pragma unroll
  for(int r=0;r<4;r++) deg[r] = min(row_fill[iw+r], CAP);
  #pragma unroll
  for(int r=0;r<4;r++){
    const unsigned short* colp = csr_col + (size_t)(iw+r)*CAP;
    cv[r] = (lane < deg[r]) ? (int)__builtin_nontemporal_load(colp + lane) : 0;
  }

  for(int r=0;r<4;r++){
    const unsigned short* colp = csr_col + (size_t)(iw+r)*CAP;
    // issue mix inputs early; they fly under the gather loop
    half4 selfv = *(const half4*)(gT + (size_t)(iw+r)*32 + 4*l8);
    half4 h0lo  = *(const half4*)(h0 + (size_t)(iw+r)*64 + 4*l8);
    half4 h0hi  = *(const half4*)(h0 + (size_t)(iw+r)*64 + 32 + 4*l8);
    float4v al  = *(const float4v*)(agg + (size_t)(iw+r)*32 + 4*l8);
    float dv    = dinv[iw+r];
    float4v acc = {0.f,0.f,0.f,0.f};
    int base = 0;
    int cur  = cv[r];
    for(;;){
      int rem = deg[r] - base; if(rem > 64) rem = 64;
      int nit = (rem + 7) >> 3;
      int it = 0;
      for(; it+2<=nit; it+=2){
        int iA = 8*it + grp, iB = iA + 8;
        int cA = __shfl(cur, iA, 64); cA = (iA < rem) ? cA : N_NODES;
        int cB = __shfl(cur, iB, 64); cB = (iB < rem) ? cB : N_NODES;
        half4 vA = *(const half4*)(gT + (size_t)cA*32 + 4*l8);
        half4 vB = *(const half4*)(gT + (size_t)cB*32 + 4*l8);
        #pragma unroll
        for(int k=0;k<4;k++) acc[k] += (float)vA[k] + (float)vB[k];
      }
      if(it < nit){
        int iA = 8*it + grp;
        int cA = __shfl(cur, iA, 64); cA = (iA < rem) ? cA : N_NODES;
        half4 vA = *(const half4*)(gT + (size_t)cA*32 + 4*l8);
        #pragma unroll
        for(int k=0;k<4;k++) acc[k] += (float)vA[k];
      }
      base += 64;
      if(base >= deg[r]) break;
      cur = (base + lane < deg[r]) ? (int)__builtin_nontemporal_load(colp + base + lane) : 0;
    }
    #pragma unroll
    for(int k=0;k<4;k++){
      acc[k] += __shfl_xor(acc[k],  8, 64);
      acc[k] += __shfl_xor(acc[k], 16, 64);
      acc[k] += __shfl_xor(acc[k], 32, 64);
    }
    if(grp == 0){
      half4 mLo, mHi;
      #pragma unroll
      for(int k=0;k<4;k++){
        mLo[k] = (_Float16)(0.9f*dv*al[k]                      + 0.1f*(float)h0lo[k]);
        mHi[k] = (_Float16)(0.9f*dv*(acc[k] + (float)selfv[k]) + 0.1f*(float)h0hi[k]);
      }
      *(half4*)&tile[(4*wave+r)*72 + 4*l8]      = mLo;
      *(half4*)&tile[(4*wave+r)*72 + 32 + 4*l8] = mHi;
    }
  }
  __syncthreads();

  float4v acc4 = {0.f,0.f,0.f,0.f};
  half8 afrag0 = *(const half8*)&tile[l15*72 + quad*8];
  half8 afrag1 = *(const half8*)&tile[l15*72 + quad*8 + 32];
  acc4 = __builtin_amdgcn_mfma_f32_16x16x32_f16(afrag0, bfrag0, acc4, 0,0,0);
  acc4 = __builtin_amdgcn_mfma_f32_16x16x32_f16(afrag1, bfrag1, acc4, 0,0,0);
  __half* outp = (n < 32) ? (goLo + n) : (goHi + (n - 32));
  #pragma unroll
  for(int r=0;r<4;r++){
    int row = quad*4 + r;
    float dvo = dinv[i0+row];
    outp[(size_t)(i0+row)*32] = __float2half(dvo*fmaxf(acc4[r], 0.f));
  }
}

// ---------------- per-edge MLP: grid-stride, one wave = 16 edges/iter, MFMA z@W2 ----------------
__global__ __launch_bounds__(256) void k_edge(const __half* __restrict__ A, const __half* __restrict__ B,
                         const int* __restrict__ srcE, const int* __restrict__ dstE,
                         const float* __restrict__ b1v, const float* __restrict__ lng,
                         const float* __restrict__ lnb, const float* __restrict__ W2,
                         const float* __restrict__ b2v, float* __restrict__ out){
  int t = threadIdx.x, wave = t>>6, lane = t&63;
  int l15 = lane&15, quad = lane>>4;

  half8 bf0, bf1;
  #pragma unroll
  for(int j=0;j<8;j++){
    float w0 = (l15<10) ? W2[(quad*8+j)*10 + l15]    : 0.f;
    float w1 = (l15<10) ? W2[(32+quad*8+j)*10 + l15] : 0.f;
    bf0[j] = (_Float16)w0;
    bf1[j] = (_Float16)w1;
  }
  float b1r0[8], b1r1[8], gr0[8], gr1[8], br0[8], br1[8];
  #pragma unroll
  for(int j=0;j<8;j++){
    b1r0[j] = b1v[quad*8+j];    b1r1[j] = b1v[32+quad*8+j];
    gr0[j]  = lng[quad*8+j];    gr1[j]  = lng[32+quad*8+j];
    br0[j]  = lnb[quad*8+j];    br1[j]  = lnb[32+quad*8+j];
  }
  float bias = (l15<10) ? b2v[l15] : 0.f;

  for(int eb = blockIdx.x*64 + wave*16; eb < N_EDGES; eb += EDGE_GRID*64){
    int e = eb + l15;
    int s = __builtin_nontemporal_load(srcE + e);
    int d = __builtin_nontemporal_load(dstE + e);
    half8 a0 = *(const half8*)(A + (size_t)s*64 + quad*8);
    half8 a1 = *(const half8*)(A + (size_t)s*64 + 32 + quad*8);
    half8 g0 = *(const half8*)(B + (size_t)d*64 + quad*8);
    half8 g1 = *(const half8*)(B + (size_t)d*64 + 32 + quad*8);
    float z0[8], z1[8];
    float s1 = 0.f, s2 = 0.f;
    #pragma unroll
    for(int j=0;j<8;j++){
      float za = (float)a0[j] + (float)g0[j] + b1r0[j];
      float zb = (float)a1[j] + (float)g1[j] + b1r1[j];
      z0[j]=za; z1[j]=zb;
      s1 += za + zb;
      s2 += za*za + zb*zb;
    }
    s1 += __shfl_xor(s1,16,64); s1 += __shfl_xor(s1,32,64);
    s2 += __shfl_xor(s2,16,64); s2 += __shfl_xor(s2,32,64);
    float mu  = s1*(1.f/64.f);
    float var = s2*(1.f/64.f) - mu*mu;
    float rs  = rsqrtf(var + 1e-5f);
    half8 af0, af1;
    #pragma unroll
    for(int j=0;j<8;j++){
      af0[j] = (_Float16)fmaxf((z0[j]-mu)*rs*gr0[j] + br0[j], 0.f);
      af1[j] = (_Float16)fmaxf((z1[j]-mu)*rs*gr1[j] + br1[j], 0.f);
    }
    float4v acc = {0.f,0.f,0.f,0.f};
    acc = __builtin_amdgcn_mfma_f32_16x16x32_f16(af0, bf0, acc, 0,0,0);
    acc = __builtin_amdgcn_mfma_f32_16x16x32_f16(af1, bf1, acc, 0,0,0);
    if(l15 < 10){
      #pragma unroll
      for(int r=0;r<4;r++){
        __builtin_nontemporal_store(acc[r] + bias, &out[(size_t)(eb + quad*4 + r)*10 + l15]);
      }
    }
  }
}

// ---------------- launch ----------------

extern "C" void kernel_launch(void* const* d_in, const int* in_sizes, int n_in,
                              void* d_out, int out_size, void* d_ws, size_t ws_size,
                              hipStream_t stream){
  const float* x     = (const float*)d_in[0];
  const float* W_lin = (const float*)d_in[1];
  const float* b_lin = (const float*)d_in[2];
  const float* Ws    = (const float*)d_in[3];
  const float* W1    = (const float*)d_in[4];
  const float* b1    = (const float*)d_in[5];
  const float* ln_g  = (const float*)d_in[6];
  const float* ln_b  = (const float*)d_in[7];
  const float* W2    = (const float*)d_in[8];
  const float* b2    = (const float*)d_in[9];
  const int*   eidx  = (const int*)d_in[10];
  const int*   rowE  = eidx;
  const int*   colE  = eidx + N_EDGES;
  float* out = (float*)d_out;

  char* ws = (char*)d_ws;
  size_t o = 0;
  auto alloc = [&](size_t bytes)->char*{ char* p = ws + o; o = (o + bytes + 255) & ~(size_t)255; return p; };
  int*   row_fill= (int*)  alloc((size_t)N_NODES*4);
  int*   degcnt  = (int*)  alloc((size_t)N_NODES*4);   // becomes rdeg (float) after k_dinv
  float* dinv    = (float*)alloc((size_t)N_NODES*4);
  unsigned short* csr_col = (unsigned short*)alloc((size_t)N_NODES*CAP*2);
  unsigned* rstream = (unsigned*)alloc((size_t)NB*BCAP*4);
  unsigned short* cstream = (unsigned short*)alloc((size_t)NB*BCAP*2);
  int*   rcur    = (int*)  alloc((size_t)NB*CURPAD*4);
  int*   ccur    = (int*)  alloc((size_t)NB*CURPAD*4);
  __half* h0     = (__half*)alloc((size_t)(N_NODES+1)*64*2);
  __half* gAlo   = (__half*)alloc((size_t)(N_NODES+1)*32*2);
  __half* gAhi   = (__half*)alloc((size_t)(N_NODES+1)*32*2);
  __half* gBlo   = (__half*)alloc((size_t)(N_NODES+1)*32*2);
  __half* gBhi   = (__half*)alloc((size_t)(N_NODES+1)*32*2);
  float* agg     = (float*)alloc((size_t)N_NODES*32*4);
  __half* Abuf   = (__half*)alloc((size_t)N_NODES*64*2);
  float* rdeg    = (float*)degcnt;

  hipMemsetAsync(rcur, 0, (size_t)NB*CURPAD*4, stream);
  hipMemsetAsync(ccur, 0, (size_t)NB*CURPAD*4, stream);

  k_bin  <<<BIN_BLOCKS, 256, 0, stream>>>(rowE, colE, rstream, cstream, rcur, ccur);
  k_build<<<2*NB, 256, 0, stream>>>(rstream, cstream, rcur, ccur, row_fill, degcnt, csr_col);
  k_dinv <<<(N_NODES+255)/256, 256, 0, stream>>>(degcnt, dinv, gAlo, gAhi, gBlo, gBhi);

  k_lin0<<<N_NODES/16, 256, 0, stream>>>(x, W_lin, b_lin, dinv, h0, gAlo, gAhi);

  const __half* ginLo = gAlo; const __half* ginHi = gAhi;
  __half* loBufs[2] = {gBlo, gAlo};
  __half* hiBufs[2] = {gBhi, gAhi};
  for(int L=0; L<8; L++){
    float beta = logf(0.5f/(float)(L+1) + 1.0f);
    k_gather<<<(N_NODES+15)/16, 256, 0, stream>>>(ginLo, row_fill, csr_col, agg);
    k_gmix  <<<(N_NODES+15)/16, 256, 0, stream>>>(ginHi, agg, h0, row_fill, csr_col, dinv,
                                                  Ws + (size_t)L*4096, beta,
                                                  loBufs[L&1], hiBufs[L&1]);
    ginLo = loBufs[L&1]; ginHi = hiBufs[L&1];
  }
  // final g in gAlo/gAhi (L=7 odd). Free for reuse: h0 only after k_ab (k_gmix used it); Abuf dedicated, Bbuf = h0.
  __half* Bbuf = h0;
  k_ab<<<N_NODES/16, 256, 0, stream>>>(gAlo, gAhi, rdeg, W1, Abuf, Bbuf);
  k_edge<<<EDGE_GRID, 256, 0, stream>>>(Abuf, Bbuf, rowE, colE, b1, ln_g, ln_b, W2, b2, out);
}

// Round 7
// 525.951 us; speedup vs baseline: 1.2231x; 1.2231x over previous
//
#include <hip/hip_runtime.h>
#include <hip/hip_fp16.h>
#include <math.h>

#define N_NODES 50000
#define N_EDGES 1600000
#define EDGE_GRID 2048
#define CAP 128   // degree capacity; mean=32 (Poisson-ish), P(deg>128)~0

// atomic-free CSR build parameters
#define NB 64            // buckets per dimension (row-buckets and col-buckets)
#define BRANGE 782       // ceil(N_NODES/NB); last bucket covers 734
#define BCAP 28672       // per-bucket stream cap; expected ~25024, sigma ~157
#define BIN_BLOCKS 512
#define EPB (N_EDGES/BIN_BLOCKS)   // 3125
#define CURPAD 32        // cursor padding: 32 ints = 128 B, one line per cursor

using half8  = __attribute__((ext_vector_type(8))) _Float16;
using half4  = __attribute__((ext_vector_type(4))) _Float16;
using float4v = __attribute__((ext_vector_type(4))) float;

__device__ __forceinline__ float rl(float v, int srclane){
  return __int_as_float(__builtin_amdgcn_readlane(__float_as_int(v), srclane));
}

// ---------------- graph setup v4: privatized build; rstream carries (e,r,c) u64 records ----------------
__global__ __launch_bounds__(256) void k_bin(const int* __restrict__ rowE, const int* __restrict__ colE,
                                             unsigned long long* __restrict__ rstream,
                                             unsigned short* __restrict__ cstream,
                                             int* __restrict__ rcur, int* __restrict__ ccur){
  __shared__ int hr[NB], hc[NB], br[NB], bc[NB];
  int t = threadIdx.x;
  if(t < NB){ hr[t] = 0; hc[t] = 0; }
  __syncthreads();
  int e0 = blockIdx.x * EPB;
  for(int e = e0 + t; e < e0 + EPB; e += 256){
    int r = __builtin_nontemporal_load(rowE + e);
    int c = __builtin_nontemporal_load(colE + e);
    atomicAdd(&hr[r/BRANGE], 1);
    atomicAdd(&hc[c/BRANGE], 1);
  }
  __syncthreads();
  if(t < NB){
    br[t] = atomicAdd(&rcur[t*CURPAD], hr[t]); hr[t] = 0;
    bc[t] = atomicAdd(&ccur[t*CURPAD], hc[t]); hc[t] = 0;
  }
  __syncthreads();
  for(int e = e0 + t; e < e0 + EPB; e += 256){
    int r = rowE[e];
    int c = colE[e];
    int rb = r/BRANGE, cb = c/BRANGE;
    int rp = br[rb] + atomicAdd(&hr[rb], 1);
    int cp = bc[cb] + atomicAdd(&hc[cb], 1);
    if(rp < BCAP) rstream[(size_t)rb*BCAP + rp] =
        ((unsigned long long)(unsigned)e << 32) | ((unsigned)r << 16) | (unsigned)c;
    if(cp < BCAP) cstream[(size_t)cb*BCAP + cp] = (unsigned short)c;
  }
}

__global__ __launch_bounds__(256) void k_build(const unsigned long long* __restrict__ rstream,
                                               const unsigned short* __restrict__ cstream,
                                               const int* __restrict__ rcur, const int* __restrict__ ccur,
                                               int* __restrict__ row_fill, int* __restrict__ degcnt,
                                               unsigned short* __restrict__ csr_col){
  __shared__ int lf[BRANGE];
  int b = blockIdx.x & (NB-1);
  int role = blockIdx.x >> 6;
  int base = b*BRANGE;
  int range = min(BRANGE, N_NODES - base);
  int t = threadIdx.x;
  for(int i=t;i<range;i+=256) lf[i] = 0;
  __syncthreads();
  if(role == 0){
    int cnt = min(rcur[b*CURPAD], BCAP);
    const unsigned long long* sp = rstream + (size_t)b*BCAP;
    for(int i=t;i<cnt;i+=256){
      unsigned long long rec = sp[i];
      int r = (int)((rec >> 16) & 0xffffu), c = (int)(rec & 0xffffu);
      int pos = atomicAdd(&lf[r-base], 1);
      if(pos < CAP) csr_col[(size_t)r*CAP + pos] = (unsigned short)c;
    }
    __syncthreads();
    for(int i=t;i<range;i+=256) row_fill[base+i] = lf[i];
  } else {
    int cnt = min(ccur[b*CURPAD], BCAP);
    const unsigned short* sp = cstream + (size_t)b*BCAP;
    for(int i=t;i<cnt;i+=256){
      int c = (int)sp[i];
      atomicAdd(&lf[c-base], 1);
    }
    __syncthreads();
    for(int i=t;i<range;i+=256) degcnt[base+i] = lf[i];
  }
}

// dinv = rsqrt(deg+1); rdeg = sqrt(deg+1) overwrites degcnt; zero row N_NODES of g tables
__global__ void k_dinv(int* __restrict__ degcnt_rdeg, float* __restrict__ dinv,
                       __half* __restrict__ gA, __half* __restrict__ gB){
  int i = blockIdx.x*256 + threadIdx.x;
  if(i < N_NODES){
    float dp1 = (float)(degcnt_rdeg[i] + 1);
    dinv[i] = rsqrtf(dp1);
    ((float*)degcnt_rdeg)[i] = sqrtf(dp1);
  }
  if(i < 64){
    gA[(size_t)N_NODES*64 + i] = __float2half(0.f);
    gB[(size_t)N_NODES*64 + i] = __float2half(0.f);
  }
}

// ---------------- lin0: h0 = relu(x @ W_lin + b); also g0 = dinv*h0 (gather table) ----------------

__global__ __launch_bounds__(256) void k_lin0(const float* __restrict__ x, const float* __restrict__ W,
                                              const float* __restrict__ b, const float* __restrict__ dinv,
                                              __half* __restrict__ h0, __half* __restrict__ g0){
  __shared__ float Wl[4096];
  int t = threadIdx.x;
  for(int i=t;i<4096;i+=256) Wl[i] = W[i];
  __syncthreads();
  int wave = t>>6, lane = t&63;
  int row0 = blockIdx.x*16 + wave*4;
  float4 xq = ((const float4*)(x + (size_t)row0*64))[lane];
  float a0=0,a1=0,a2=0,a3=0;
  #pragma unroll
  for(int k=0;k<64;k++){
    float w = Wl[k*64+lane];
    float comp = ((k&3)==0)?xq.x:((k&3)==1)?xq.y:((k&3)==2)?xq.z:xq.w;
    a0 += rl(comp,      (k>>2)) * w;
    a1 += rl(comp, 16 + (k>>2)) * w;
    a2 += rl(comp, 32 + (k>>2)) * w;
    a3 += rl(comp, 48 + (k>>2)) * w;
  }
  float bb = b[lane];
  float h[4] = {fmaxf(a0+bb,0.f), fmaxf(a1+bb,0.f), fmaxf(a2+bb,0.f), fmaxf(a3+bb,0.f)};
  #pragma unroll
  for(int r=0;r<4;r++){
    float dv = dinv[row0+r];
    h0[(size_t)(row0+r)*64+lane] = __float2half(h[r]);
    g0[(size_t)(row0+r)*64+lane] = __float2half(dv*h[r]);
  }
}

// A = h @ W1[:64], B = h @ W1[64:], h reconstructed as g*rdeg (fp16 in/out)
__global__ __launch_bounds__(256) void k_ab(const __half* __restrict__ g, const float* __restrict__ rdeg,
                                            const float* __restrict__ W1,
                                            __half* __restrict__ A, __half* __restrict__ B){
  __shared__ float Wa[4096];
  __shared__ float Wb[4096];
  int t = threadIdx.x;
  for(int i=t;i<4096;i+=256){ Wa[i] = W1[i]; Wb[i] = W1[4096+i]; }
  __syncthreads();
  int wave = t>>6, lane = t&63;
  int row0 = blockIdx.x*16 + wave*4;
  int myrow = row0 + (lane>>4);
  float rd = rdeg[myrow];
  const __half2* hp = (const __half2*)(g + (size_t)row0*64);
  __half2 p01 = hp[2*lane], p23 = hp[2*lane+1];
  float2 f01 = __half22float2(p01), f23 = __half22float2(p23);
  float4 xq = make_float4(f01.x*rd, f01.y*rd, f23.x*rd, f23.y*rd);
  float a0=0,a1=0,a2=0,a3=0,b0=0,b1=0,b2=0,b3=0;
  #pragma unroll
  for(int k=0;k<64;k++){
    float wa = Wa[k*64+lane], wb = Wb[k*64+lane];
    float comp = ((k&3)==0)?xq.x:((k&3)==1)?xq.y:((k&3)==2)?xq.z:xq.w;
    float s0 = rl(comp,      (k>>2));
    float s1 = rl(comp, 16 + (k>>2));
    float s2 = rl(comp, 32 + (k>>2));
    float s3 = rl(comp, 48 + (k>>2));
    a0 += s0*wa; a1 += s1*wa; a2 += s2*wa; a3 += s3*wa;
    b0 += s0*wb; b1 += s1*wb; b2 += s2*wb; b3 += s3*wb;
  }
  A[(size_t)(row0+0)*64+lane]=__float2half(a0); A[(size_t)(row0+1)*64+lane]=__float2half(a1);
  A[(size_t)(row0+2)*64+lane]=__float2half(a2); A[(size_t)(row0+3)*64+lane]=__float2half(a3);
  B[(size_t)(row0+0)*64+lane]=__float2half(b0); B[(size_t)(row0+1)*64+lane]=__float2half(b1);
  B[(size_t)(row0+2)*64+lane]=__float2half(b2); B[(size_t)(row0+3)*64+lane]=__float2half(b3);
}

// ---------------- fused GCN2 layer v9 (best measured): quad/half4, 4 independent gathers ----------------
__global__ __launch_bounds__(256) void k_layer(const __half* __restrict__ g_in, const __half* __restrict__ h0,
                          const int* __restrict__ row_fill, const unsigned short* __restrict__ csr_col,
                          const float* __restrict__ dinv,
                          const float* __restrict__ Wsl, float beta, __half* __restrict__ g_out){
  __shared__ __align__(16) _Float16 tile[16*72];
  int t = threadIdx.x, wave = t>>6, lane = t&63;
  int quad = lane>>4, l15 = lane&15;

  half8 bfrag0, bfrag1;
  int n = 16*wave + l15;
  #pragma unroll
  for(int j=0;j<8;j++){
    int k0 = quad*8 + j;
    int k1 = 32 + quad*8 + j;
    bfrag0[j] = (_Float16)(beta*Wsl[k0*64+n] + ((k0==n)?(1.f-beta):0.f));
    bfrag1[j] = (_Float16)(beta*Wsl[k1*64+n] + ((k1==n)?(1.f-beta):0.f));
  }

  int i0 = blockIdx.x*16;
  int iw = i0 + 4*wave;

  int deg[4], cv[4];
  half4 selfv[4], h0v[4];
  float dv[4];
  #pragma unroll
  for(int r=0;r<4;r++) deg[r] = min(row_fill[iw+r], CAP);
  #pragma unroll
  for(int r=0;r<4;r++){
    const unsigned short* colp = csr_col + (size_t)(iw+r)*CAP;
    cv[r] = (lane < deg[r]) ? (int)__builtin_nontemporal_load(colp + lane) : 0;
  }
  #pragma unroll
  for(int r=0;r<4;r++){
    dv[r]    = dinv[iw+r];
    selfv[r] = *(const half4*)(g_in + (size_t)(iw+r)*64 + 4*l15);
    h0v[r]   = *(const half4*)(h0   + (size_t)(iw+r)*64 + 4*l15);
  }

  for(int r=0;r<4;r++){
    const unsigned short* colp = csr_col + (size_t)(iw+r)*CAP;
    float4v acc = {0.f,0.f,0.f,0.f};
    int base = 0;
    int cur  = cv[r];
    for(;;){
      int rem = deg[r] - base; if(rem > 64) rem = 64;
      int nit = (rem + 3) >> 2;
      int it = 0;
      for(; it+4<=nit; it+=4){
        int i0x = 4*it + quad, i1x = i0x+4, i2x = i0x+8, i3x = i0x+12;
        int c0 = __shfl(cur, i0x, 64); c0 = (i0x < rem) ? c0 : N_NODES;
        int c1 = __shfl(cur, i1x, 64); c1 = (i1x < rem) ? c1 : N_NODES;
        int c2 = __shfl(cur, i2x, 64); c2 = (i2x < rem) ? c2 : N_NODES;
        int c3 = __shfl(cur, i3x, 64); c3 = (i3x < rem) ? c3 : N_NODES;
        half4 v0 = *(const half4*)(g_in + (size_t)c0*64 + 4*l15);
        half4 v1 = *(const half4*)(g_in + (size_t)c1*64 + 4*l15);
        half4 v2 = *(const half4*)(g_in + (size_t)c2*64 + 4*l15);
        half4 v3 = *(const half4*)(g_in + (size_t)c3*64 + 4*l15);
        #pragma unroll
        for(int k=0;k<4;k++) acc[k] += ((float)v0[k]+(float)v1[k]) + ((float)v2[k]+(float)v3[k]);
      }
      for(; it+2<=nit; it+=2){
        int i0x = 4*it + quad, i1x = i0x+4;
        int c0 = __shfl(cur, i0x, 64); c0 = (i0x < rem) ? c0 : N_NODES;
        int c1 = __shfl(cur, i1x, 64); c1 = (i1x < rem) ? c1 : N_NODES;
        half4 v0 = *(const half4*)(g_in + (size_t)c0*64 + 4*l15);
        half4 v1 = *(const half4*)(g_in + (size_t)c1*64 + 4*l15);
        #pragma unroll
        for(int k=0;k<4;k++) acc[k] += (float)v0[k] + (float)v1[k];
      }
      if(it < nit){
        int i0x = 4*it + quad;
        int c0 = __shfl(cur, i0x, 64); c0 = (i0x < rem) ? c0 : N_NODES;
        half4 v0 = *(const half4*)(g_in + (size_t)c0*64 + 4*l15);
        #pragma unroll
        for(int k=0;k<4;k++) acc[k] += (float)v0[k];
      }
      base += 64;
      if(base >= deg[r]) break;
      cur = (base + lane < deg[r]) ? (int)__builtin_nontemporal_load(colp + base + lane) : 0;
    }
    #pragma unroll
    for(int k=0;k<4;k++){
      acc[k] += __shfl_xor(acc[k], 16, 64);
      acc[k] += __shfl_xor(acc[k], 32, 64);
    }
    if(quad == 0){
      half4 mixv;
      #pragma unroll
      for(int k=0;k<4;k++){
        float m = 0.9f*dv[r]*(acc[k] + (float)selfv[r][k]) + 0.1f*(float)h0v[r][k];
        mixv[k] = (_Float16)m;
      }
      *(half4*)&tile[(4*wave+r)*72 + 4*l15] = mixv;
    }
  }
  __syncthreads();

  float4v acc4 = {0.f,0.f,0.f,0.f};
  half8 afrag0 = *(const half8*)&tile[l15*72 + quad*8];
  half8 afrag1 = *(const half8*)&tile[l15*72 + quad*8 + 32];
  acc4 = __builtin_amdgcn_mfma_f32_16x16x32_f16(afrag0, bfrag0, acc4, 0,0,0);
  acc4 = __builtin_amdgcn_mfma_f32_16x16x32_f16(afrag1, bfrag1, acc4, 0,0,0);
  #pragma unroll
  for(int r=0;r<4;r++){
    int row = quad*4 + r;
    float dvo = dinv[i0+row];
    g_out[(size_t)(i0+row)*64 + n] = __float2half(dvo*fmaxf(acc4[r], 0.f));
  }
}

// ---------------- per-edge MLP v3b: src-bucket-major, L2-resident A slice per XCD ----------------
// Fix vs v3: edge-id shuffles hoisted OUT of the divergent l15<10 branch (shfl from an
// inactive lane is undefined on CDNA — was the round-6 correctness failure).
__global__ __launch_bounds__(256) void k_edge(const __half* __restrict__ A, const __half* __restrict__ B,
                         const unsigned long long* __restrict__ rstream, const int* __restrict__ rcur,
                         const float* __restrict__ b1v, const float* __restrict__ lng,
                         const float* __restrict__ lnb, const float* __restrict__ W2,
                         const float* __restrict__ b2v, float* __restrict__ out){
  int t = threadIdx.x, wave = t>>6, lane = t&63;
  int l15 = lane&15, quad = lane>>4;

  half8 bf0, bf1;
  #pragma unroll
  for(int j=0;j<8;j++){
    float w0 = (l15<10) ? W2[(quad*8+j)*10 + l15]    : 0.f;
    float w1 = (l15<10) ? W2[(32+quad*8+j)*10 + l15] : 0.f;
    bf0[j] = (_Float16)w0;
    bf1[j] = (_Float16)w1;
  }
  float b1r0[8], b1r1[8], gr0[8], gr1[8], br0[8], br1[8];
  #pragma unroll
  for(int j=0;j<8;j++){
    b1r0[j] = b1v[quad*8+j];    b1r1[j] = b1v[32+quad*8+j];
    gr0[j]  = lng[quad*8+j];    gr1[j]  = lng[32+quad*8+j];
    br0[j]  = lnb[quad*8+j];    br1[j]  = lnb[32+quad*8+j];
  }
  float bias = (l15<10) ? b2v[l15] : 0.f;

  int bid = blockIdx.x;
  int bucket = ((bid & 7) << 3) | ((bid >> 3) & 7);   // XCD x -> buckets 8x..8x+7
  int sub = bid >> 6;                                  // 0..31
  int cnt = rcur[bucket*CURPAD]; if(cnt > BCAP) cnt = BCAP;
  const unsigned long long* sp = rstream + (size_t)bucket*BCAP;
  int chunk = ((cnt + 2047) >> 11) << 6;               // ceil(cnt/2048)*64, multiple of 64
  int start = sub*chunk;
  int end = start + chunk; if(end > cnt) end = cnt;

  for(int eo = start + wave*16; eo < end; eo += 64){
    int idx = eo + l15; if(idx >= end) idx = end - 1;
    unsigned long long rec = sp[idx];
    int s = (int)((rec >> 16) & 0xffffu);
    int d = (int)(rec & 0xffffu);
    int e = (int)(rec >> 32);
    half8 a0 = *(const half8*)(A + (size_t)s*64 + quad*8);
    half8 a1 = *(const half8*)(A + (size_t)s*64 + 32 + quad*8);
    half8 g0 = *(const half8*)(B + (size_t)d*64 + quad*8);
    half8 g1 = *(const half8*)(B + (size_t)d*64 + 32 + quad*8);
    float z0[8], z1[8];
    float s1 = 0.f, s2 = 0.f;
    #pragma unroll
    for(int j=0;j<8;j++){
      float za = (float)a0[j] + (float)g0[j] + b1r0[j];
      float zb = (float)a1[j] + (float)g1[j] + b1r1[j];
      z0[j]=za; z1[j]=zb;
      s1 += za + zb;
      s2 += za*za + zb*zb;
    }
    s1 += __shfl_xor(s1,16,64); s1 += __shfl_xor(s1,32,64);
    s2 += __shfl_xor(s2,16,64); s2 += __shfl_xor(s2,32,64);
    float mu  = s1*(1.f/64.f);
    float var = s2*(1.f/64.f) - mu*mu;
    float rs  = rsqrtf(var + 1e-5f);
    half8 af0, af1;
    #pragma unroll
    for(int j=0;j<8;j++){
      af0[j] = (_Float16)fmaxf((z0[j]-mu)*rs*gr0[j] + br0[j], 0.f);
      af1[j] = (_Float16)fmaxf((z1[j]-mu)*rs*gr1[j] + br1[j], 0.f);
    }
    float4v acc = {0.f,0.f,0.f,0.f};
    acc = __builtin_amdgcn_mfma_f32_16x16x32_f16(af0, bf0, acc, 0,0,0);
    acc = __builtin_amdgcn_mfma_f32_16x16x32_f16(af1, bf1, acc, 0,0,0);
    // shuffle edge ids for this quad's 4 output rows with ALL lanes active
    int esl[4];
    #pragma unroll
    for(int r=0;r<4;r++) esl[r] = __shfl(e, quad*4 + r, 64);
    if(l15 < 10){
      #pragma unroll
      for(int r=0;r<4;r++){
        if(eo + quad*4 + r < end)
          __builtin_nontemporal_store(acc[r] + bias, &out[(size_t)esl[r]*10 + l15]);
      }
    }
  }
}

// ---------------- launch ----------------

extern "C" void kernel_launch(void* const* d_in, const int* in_sizes, int n_in,
                              void* d_out, int out_size, void* d_ws, size_t ws_size,
                              hipStream_t stream){
  const float* x     = (const float*)d_in[0];
  const float* W_lin = (const float*)d_in[1];
  const float* b_lin = (const float*)d_in[2];
  const float* Ws    = (const float*)d_in[3];
  const float* W1    = (const float*)d_in[4];
  const float* b1    = (const float*)d_in[5];
  const float* ln_g  = (const float*)d_in[6];
  const float* ln_b  = (const float*)d_in[7];
  const float* W2    = (const float*)d_in[8];
  const float* b2    = (const float*)d_in[9];
  const int*   eidx  = (const int*)d_in[10];
  const int*   rowE  = eidx;
  const int*   colE  = eidx + N_EDGES;
  float* out = (float*)d_out;

  char* ws = (char*)d_ws;
  size_t o = 0;
  auto alloc = [&](size_t bytes)->char*{ char* p = ws + o; o = (o + bytes + 255) & ~(size_t)255; return p; };
  int*   row_fill= (int*)  alloc((size_t)N_NODES*4);
  int*   degcnt  = (int*)  alloc((size_t)N_NODES*4);   // becomes rdeg (float) after k_dinv
  float* dinv    = (float*)alloc((size_t)N_NODES*4);
  unsigned short* csr_col = (unsigned short*)alloc((size_t)N_NODES*CAP*2);
  unsigned long long* rstream = (unsigned long long*)alloc((size_t)NB*BCAP*8);
  unsigned short* cstream = (unsigned short*)alloc((size_t)NB*BCAP*2);
  int*   rcur    = (int*)  alloc((size_t)NB*CURPAD*4);
  int*   ccur    = (int*)  alloc((size_t)NB*CURPAD*4);
  __half* h0     = (__half*)alloc((size_t)(N_NODES+1)*64*2);
  __half* gA     = (__half*)alloc((size_t)(N_NODES+1)*64*2);
  __half* gB     = (__half*)alloc((size_t)(N_NODES+1)*64*2);
  float* rdeg    = (float*)degcnt;

  hipMemsetAsync(rcur, 0, (size_t)NB*CURPAD*4, stream);
  hipMemsetAsync(ccur, 0, (size_t)NB*CURPAD*4, stream);

  k_bin  <<<BIN_BLOCKS, 256, 0, stream>>>(rowE, colE, rstream, cstream, rcur, ccur);
  k_build<<<2*NB, 256, 0, stream>>>(rstream, cstream, rcur, ccur, row_fill, degcnt, csr_col);
  k_dinv <<<(N_NODES+255)/256, 256, 0, stream>>>(degcnt, dinv, gA, gB);

  k_lin0<<<N_NODES/16, 256, 0, stream>>>(x, W_lin, b_lin, dinv, h0, gA);

  const __half* gin = gA;
  __half* bufs[2] = {gB, gA};
  for(int L=0; L<8; L++){
    float beta = logf(0.5f/(float)(L+1) + 1.0f);
    __half* gout = bufs[L&1];
    k_layer<<<(N_NODES+15)/16, 256, 0, stream>>>(gin, h0, row_fill, csr_col, dinv,
                                                 Ws + (size_t)L*4096, beta, gout);
    gin = gout;
  }
  // final g is bufs[1] = gA (layer 7). Free: gB, h0 -> reuse for A,B.
  __half* Abuf = gB;
  __half* Bbuf = h0;
  k_ab<<<N_NODES/16, 256, 0, stream>>>(gA, rdeg, W1, Abuf, Bbuf);
  k_edge<<<EDGE_GRID, 256, 0, stream>>>(Abuf, Bbuf, rstream, rcur, b1, ln_g, ln_b, W2, b2, out);
}

// Round 8
// 501.779 us; speedup vs baseline: 1.2820x; 1.0482x over previous
//
#include <hip/hip_runtime.h>
#include <hip/hip_fp16.h>
#include <math.h>

#define N_NODES 50000
#define N_EDGES 1600000
#define EDGE_GRID 2048
#define CAP 128   // degree capacity; mean=32 (Poisson-ish), P(deg>128)~0

// atomic-free CSR build parameters
#define NB 64            // buckets per dimension (row-buckets and col-buckets)
#define BRANGE 782       // ceil(N_NODES/NB); last bucket covers 734
#define BCAP 28672       // per-bucket stream cap; expected ~25024, sigma ~157
#define BIN_BLOCKS 512
#define EPB (N_EDGES/BIN_BLOCKS)   // 3125
#define CURPAD 32        // cursor padding: 32 ints = 128 B, one line per cursor

using half8  = __attribute__((ext_vector_type(8))) _Float16;
using half4  = __attribute__((ext_vector_type(4))) _Float16;
using float4v = __attribute__((ext_vector_type(4))) float;

__device__ __forceinline__ float rl(float v, int srclane){
  return __int_as_float(__builtin_amdgcn_readlane(__float_as_int(v), srclane));
}

// ---------------- graph setup v3 (u32 records): fully privatized, no random global atomics ----------------
__global__ __launch_bounds__(256) void k_bin(const int* __restrict__ rowE, const int* __restrict__ colE,
                                             unsigned* __restrict__ rstream, unsigned short* __restrict__ cstream,
                                             int* __restrict__ rcur, int* __restrict__ ccur){
  __shared__ int hr[NB], hc[NB], br[NB], bc[NB];
  int t = threadIdx.x;
  if(t < NB){ hr[t] = 0; hc[t] = 0; }
  __syncthreads();
  int e0 = blockIdx.x * EPB;
  for(int e = e0 + t; e < e0 + EPB; e += 256){
    int r = __builtin_nontemporal_load(rowE + e);
    int c = __builtin_nontemporal_load(colE + e);
    atomicAdd(&hr[r/BRANGE], 1);
    atomicAdd(&hc[c/BRANGE], 1);
  }
  __syncthreads();
  if(t < NB){
    br[t] = atomicAdd(&rcur[t*CURPAD], hr[t]); hr[t] = 0;
    bc[t] = atomicAdd(&ccur[t*CURPAD], hc[t]); hc[t] = 0;
  }
  __syncthreads();
  for(int e = e0 + t; e < e0 + EPB; e += 256){
    int r = rowE[e];
    int c = colE[e];
    int rb = r/BRANGE, cb = c/BRANGE;
    int rp = br[rb] + atomicAdd(&hr[rb], 1);
    int cp = bc[cb] + atomicAdd(&hc[cb], 1);
    if(rp < BCAP) rstream[(size_t)rb*BCAP + rp] = ((unsigned)r << 16) | (unsigned)c;
    if(cp < BCAP) cstream[(size_t)cb*BCAP + cp] = (unsigned short)c;
  }
}

__global__ __launch_bounds__(256) void k_build(const unsigned* __restrict__ rstream,
                                               const unsigned short* __restrict__ cstream,
                                               const int* __restrict__ rcur, const int* __restrict__ ccur,
                                               int* __restrict__ row_fill, int* __restrict__ degcnt,
                                               unsigned short* __restrict__ csr_col){
  __shared__ int lf[BRANGE];
  int b = blockIdx.x & (NB-1);
  int role = blockIdx.x >> 6;
  int base = b*BRANGE;
  int range = min(BRANGE, N_NODES - base);
  int t = threadIdx.x;
  for(int i=t;i<range;i+=256) lf[i] = 0;
  __syncthreads();
  if(role == 0){
    int cnt = min(rcur[b*CURPAD], BCAP);
    const unsigned* sp = rstream + (size_t)b*BCAP;
    for(int i=t;i<cnt;i+=256){
      unsigned rc = sp[i];
      int r = (int)(rc >> 16), c = (int)(rc & 0xffffu);
      int pos = atomicAdd(&lf[r-base], 1);
      if(pos < CAP) csr_col[(size_t)r*CAP + pos] = (unsigned short)c;
    }
    __syncthreads();
    for(int i=t;i<range;i+=256) row_fill[base+i] = lf[i];
  } else {
    int cnt = min(ccur[b*CURPAD], BCAP);
    const unsigned short* sp = cstream + (size_t)b*BCAP;
    for(int i=t;i<cnt;i+=256){
      int c = (int)sp[i];
      atomicAdd(&lf[c-base], 1);
    }
    __syncthreads();
    for(int i=t;i<range;i+=256) degcnt[base+i] = lf[i];
  }
}

// dinv = rsqrt(deg+1); rdeg = sqrt(deg+1) overwrites degcnt; zero row N_NODES of g tables
__global__ void k_dinv(int* __restrict__ degcnt_rdeg, float* __restrict__ dinv,
                       __half* __restrict__ gA, __half* __restrict__ gB){
  int i = blockIdx.x*256 + threadIdx.x;
  if(i < N_NODES){
    float dp1 = (float)(degcnt_rdeg[i] + 1);
    dinv[i] = rsqrtf(dp1);
    ((float*)degcnt_rdeg)[i] = sqrtf(dp1);
  }
  if(i < 64){
    gA[(size_t)N_NODES*64 + i] = __float2half(0.f);
    gB[(size_t)N_NODES*64 + i] = __float2half(0.f);
  }
}

// ---------------- lin0: h0 = relu(x @ W_lin + b); also g0 = dinv*h0 (gather table) ----------------

__global__ __launch_bounds__(256) void k_lin0(const float* __restrict__ x, const float* __restrict__ W,
                                              const float* __restrict__ b, const float* __restrict__ dinv,
                                              __half* __restrict__ h0, __half* __restrict__ g0){
  __shared__ float Wl[4096];
  int t = threadIdx.x;
  for(int i=t;i<4096;i+=256) Wl[i] = W[i];
  __syncthreads();
  int wave = t>>6, lane = t&63;
  int row0 = blockIdx.x*16 + wave*4;
  float4 xq = ((const float4*)(x + (size_t)row0*64))[lane];
  float a0=0,a1=0,a2=0,a3=0;
  #pragma unroll
  for(int k=0;k<64;k++){
    float w = Wl[k*64+lane];
    float comp = ((k&3)==0)?xq.x:((k&3)==1)?xq.y:((k&3)==2)?xq.z:xq.w;
    a0 += rl(comp,      (k>>2)) * w;
    a1 += rl(comp, 16 + (k>>2)) * w;
    a2 += rl(comp, 32 + (k>>2)) * w;
    a3 += rl(comp, 48 + (k>>2)) * w;
  }
  float bb = b[lane];
  float h[4] = {fmaxf(a0+bb,0.f), fmaxf(a1+bb,0.f), fmaxf(a2+bb,0.f), fmaxf(a3+bb,0.f)};
  #pragma unroll
  for(int r=0;r<4;r++){
    float dv = dinv[row0+r];
    h0[(size_t)(row0+r)*64+lane] = __float2half(h[r]);
    g0[(size_t)(row0+r)*64+lane] = __float2half(dv*h[r]);
  }
}

// A = h @ W1[:64], B = h @ W1[64:], h reconstructed as g*rdeg (fp16 in/out)
__global__ __launch_bounds__(256) void k_ab(const __half* __restrict__ g, const float* __restrict__ rdeg,
                                            const float* __restrict__ W1,
                                            __half* __restrict__ A, __half* __restrict__ B){
  __shared__ float Wa[4096];
  __shared__ float Wb[4096];
  int t = threadIdx.x;
  for(int i=t;i<4096;i+=256){ Wa[i] = W1[i]; Wb[i] = W1[4096+i]; }
  __syncthreads();
  int wave = t>>6, lane = t&63;
  int row0 = blockIdx.x*16 + wave*4;
  int myrow = row0 + (lane>>4);
  float rd = rdeg[myrow];
  const __half2* hp = (const __half2*)(g + (size_t)row0*64);
  __half2 p01 = hp[2*lane], p23 = hp[2*lane+1];
  float2 f01 = __half22float2(p01), f23 = __half22float2(p23);
  float4 xq = make_float4(f01.x*rd, f01.y*rd, f23.x*rd, f23.y*rd);
  float a0=0,a1=0,a2=0,a3=0,b0=0,b1=0,b2=0,b3=0;
  #pragma unroll
  for(int k=0;k<64;k++){
    float wa = Wa[k*64+lane], wb = Wb[k*64+lane];
    float comp = ((k&3)==0)?xq.x:((k&3)==1)?xq.y:((k&3)==2)?xq.z:xq.w;
    float s0 = rl(comp,      (k>>2));
    float s1 = rl(comp, 16 + (k>>2));
    float s2 = rl(comp, 32 + (k>>2));
    float s3 = rl(comp, 48 + (k>>2));
    a0 += s0*wa; a1 += s1*wa; a2 += s2*wa; a3 += s3*wa;
    b0 += s0*wb; b1 += s1*wb; b2 += s2*wb; b3 += s3*wb;
  }
  A[(size_t)(row0+0)*64+lane]=__float2half(a0); A[(size_t)(row0+1)*64+lane]=__float2half(a1);
  A[(size_t)(row0+2)*64+lane]=__float2half(a2); A[(size_t)(row0+3)*64+lane]=__float2half(a3);
  B[(size_t)(row0+0)*64+lane]=__float2half(b0); B[(size_t)(row0+1)*64+lane]=__float2half(b1);
  B[(size_t)(row0+2)*64+lane]=__float2half(b2); B[(size_t)(row0+3)*64+lane]=__float2half(b3);
}

// ---------------- fused GCN2 layer v9 (best measured): quad/half4, 4 independent gathers ----------------
__global__ __launch_bounds__(256) void k_layer(const __half* __restrict__ g_in, const __half* __restrict__ h0,
                          const int* __restrict__ row_fill, const unsigned short* __restrict__ csr_col,
                          const float* __restrict__ dinv,
                          const float* __restrict__ Wsl, float beta, __half* __restrict__ g_out){
  __shared__ __align__(16) _Float16 tile[16*72];
  int t = threadIdx.x, wave = t>>6, lane = t&63;
  int quad = lane>>4, l15 = lane&15;

  half8 bfrag0, bfrag1;
  int n = 16*wave + l15;
  #pragma unroll
  for(int j=0;j<8;j++){
    int k0 = quad*8 + j;
    int k1 = 32 + quad*8 + j;
    bfrag0[j] = (_Float16)(beta*Wsl[k0*64+n] + ((k0==n)?(1.f-beta):0.f));
    bfrag1[j] = (_Float16)(beta*Wsl[k1*64+n] + ((k1==n)?(1.f-beta):0.f));
  }

  int i0 = blockIdx.x*16;
  int iw = i0 + 4*wave;

  int deg[4], cv[4];
  half4 selfv[4], h0v[4];
  float dv[4];
  #pragma unroll
  for(int r=0;r<4;r++) deg[r] = min(row_fill[iw+r], CAP);
  #pragma unroll
  for(int r=0;r<4;r++){
    const unsigned short* colp = csr_col + (size_t)(iw+r)*CAP;
    cv[r] = (lane < deg[r]) ? (int)__builtin_nontemporal_load(colp + lane) : 0;
  }
  #pragma unroll
  for(int r=0;r<4;r++){
    dv[r]    = dinv[iw+r];
    selfv[r] = *(const half4*)(g_in + (size_t)(iw+r)*64 + 4*l15);
    h0v[r]   = *(const half4*)(h0   + (size_t)(iw+r)*64 + 4*l15);
  }

  for(int r=0;r<4;r++){
    const unsigned short* colp = csr_col + (size_t)(iw+r)*CAP;
    float4v acc = {0.f,0.f,0.f,0.f};
    int base = 0;
    int cur  = cv[r];
    for(;;){
      int rem = deg[r] - base; if(rem > 64) rem = 64;
      int nit = (rem + 3) >> 2;
      int it = 0;
      for(; it+4<=nit; it+=4){
        int i0x = 4*it + quad, i1x = i0x+4, i2x = i0x+8, i3x = i0x+12;
        int c0 = __shfl(cur, i0x, 64); c0 = (i0x < rem) ? c0 : N_NODES;
        int c1 = __shfl(cur, i1x, 64); c1 = (i1x < rem) ? c1 : N_NODES;
        int c2 = __shfl(cur, i2x, 64); c2 = (i2x < rem) ? c2 : N_NODES;
        int c3 = __shfl(cur, i3x, 64); c3 = (i3x < rem) ? c3 : N_NODES;
        half4 v0 = *(const half4*)(g_in + (size_t)c0*64 + 4*l15);
        half4 v1 = *(const half4*)(g_in + (size_t)c1*64 + 4*l15);
        half4 v2 = *(const half4*)(g_in + (size_t)c2*64 + 4*l15);
        half4 v3 = *(const half4*)(g_in + (size_t)c3*64 + 4*l15);
        #pragma unroll
        for(int k=0;k<4;k++) acc[k] += ((float)v0[k]+(float)v1[k]) + ((float)v2[k]+(float)v3[k]);
      }
      for(; it+2<=nit; it+=2){
        int i0x = 4*it + quad, i1x = i0x+4;
        int c0 = __shfl(cur, i0x, 64); c0 = (i0x < rem) ? c0 : N_NODES;
        int c1 = __shfl(cur, i1x, 64); c1 = (i1x < rem) ? c1 : N_NODES;
        half4 v0 = *(const half4*)(g_in + (size_t)c0*64 + 4*l15);
        half4 v1 = *(const half4*)(g_in + (size_t)c1*64 + 4*l15);
        #pragma unroll
        for(int k=0;k<4;k++) acc[k] += (float)v0[k] + (float)v1[k];
      }
      if(it < nit){
        int i0x = 4*it + quad;
        int c0 = __shfl(cur, i0x, 64); c0 = (i0x < rem) ? c0 : N_NODES;
        half4 v0 = *(const half4*)(g_in + (size_t)c0*64 + 4*l15);
        #pragma unroll
        for(int k=0;k<4;k++) acc[k] += (float)v0[k];
      }
      base += 64;
      if(base >= deg[r]) break;
      cur = (base + lane < deg[r]) ? (int)__builtin_nontemporal_load(colp + base + lane) : 0;
    }
    #pragma unroll
    for(int k=0;k<4;k++){
      acc[k] += __shfl_xor(acc[k], 16, 64);
      acc[k] += __shfl_xor(acc[k], 32, 64);
    }
    if(quad == 0){
      half4 mixv;
      #pragma unroll
      for(int k=0;k<4;k++){
        float m = 0.9f*dv[r]*(acc[k] + (float)selfv[r][k]) + 0.1f*(float)h0v[r][k];
        mixv[k] = (_Float16)m;
      }
      *(half4*)&tile[(4*wave+r)*72 + 4*l15] = mixv;
    }
  }
  __syncthreads();

  float4v acc4 = {0.f,0.f,0.f,0.f};
  half8 afrag0 = *(const half8*)&tile[l15*72 + quad*8];
  half8 afrag1 = *(const half8*)&tile[l15*72 + quad*8 + 32];
  acc4 = __builtin_amdgcn_mfma_f32_16x16x32_f16(afrag0, bfrag0, acc4, 0,0,0);
  acc4 = __builtin_amdgcn_mfma_f32_16x16x32_f16(afrag1, bfrag1, acc4, 0,0,0);
  #pragma unroll
  for(int r=0;r<4;r++){
    int row = quad*4 + r;
    float dvo = dinv[i0+row];
    g_out[(size_t)(i0+row)*64 + n] = __float2half(dvo*fmaxf(acc4[r], 0.f));
  }
}

// ---------------- per-edge MLP (sequential order, best measured): 16 edges/wave, MFMA z@W2 ----------------
__global__ __launch_bounds__(256) void k_edge(const __half* __restrict__ A, const __half* __restrict__ B,
                         const int* __restrict__ srcE, const int* __restrict__ dstE,
                         const float* __restrict__ b1v, const float* __restrict__ lng,
                         const float* __restrict__ lnb, const float* __restrict__ W2,
                         const float* __restrict__ b2v, float* __restrict__ out){
  int t = threadIdx.x, wave = t>>6, lane = t&63;
  int l15 = lane&15, quad = lane>>4;

  half8 bf0, bf1;
  #pragma unroll
  for(int j=0;j<8;j++){
    float w0 = (l15<10) ? W2[(quad*8+j)*10 + l15]    : 0.f;
    float w1 = (l15<10) ? W2[(32+quad*8+j)*10 + l15] : 0.f;
    bf0[j] = (_Float16)w0;
    bf1[j] = (_Float16)w1;
  }
  float b1r0[8], b1r1[8], gr0[8], gr1[8], br0[8], br1[8];
  #pragma unroll
  for(int j=0;j<8;j++){
    b1r0[j] = b1v[quad*8+j];    b1r1[j] = b1v[32+quad*8+j];
    gr0[j]  = lng[quad*8+j];    gr1[j]  = lng[32+quad*8+j];
    br0[j]  = lnb[quad*8+j];    br1[j]  = lnb[32+quad*8+j];
  }
  float bias = (l15<10) ? b2v[l15] : 0.f;

  for(int eb = blockIdx.x*64 + wave*16; eb < N_EDGES; eb += EDGE_GRID*64){
    int e = eb + l15;
    int s = __builtin_nontemporal_load(srcE + e);
    int d = __builtin_nontemporal_load(dstE + e);
    half8 a0 = *(const half8*)(A + (size_t)s*64 + quad*8);
    half8 a1 = *(const half8*)(A + (size_t)s*64 + 32 + quad*8);
    half8 g0 = *(const half8*)(B + (size_t)d*64 + quad*8);
    half8 g1 = *(const half8*)(B + (size_t)d*64 + 32 + quad*8);
    float z0[8], z1[8];
    float s1 = 0.f, s2 = 0.f;
    #pragma unroll
    for(int j=0;j<8;j++){
      float za = (float)a0[j] + (float)g0[j] + b1r0[j];
      float zb = (float)a1[j] + (float)g1[j] + b1r1[j];
      z0[j]=za; z1[j]=zb;
      s1 += za + zb;
      s2 += za*za + zb*zb;
    }
    s1 += __shfl_xor(s1,16,64); s1 += __shfl_xor(s1,32,64);
    s2 += __shfl_xor(s2,16,64); s2 += __shfl_xor(s2,32,64);
    float mu  = s1*(1.f/64.f);
    float var = s2*(1.f/64.f) - mu*mu;
    float rs  = rsqrtf(var + 1e-5f);
    half8 af0, af1;
    #pragma unroll
    for(int j=0;j<8;j++){
      af0[j] = (_Float16)fmaxf((z0[j]-mu)*rs*gr0[j] + br0[j], 0.f);
      af1[j] = (_Float16)fmaxf((z1[j]-mu)*rs*gr1[j] + br1[j], 0.f);
    }
    float4v acc = {0.f,0.f,0.f,0.f};
    acc = __builtin_amdgcn_mfma_f32_16x16x32_f16(af0, bf0, acc, 0,0,0);
    acc = __builtin_amdgcn_mfma_f32_16x16x32_f16(af1, bf1, acc, 0,0,0);
    if(l15 < 10){
      #pragma unroll
      for(int r=0;r<4;r++){
        __builtin_nontemporal_store(acc[r] + bias, &out[(size_t)(eb + quad*4 + r)*10 + l15]);
      }
    }
  }
}

// ---------------- launch ----------------

extern "C" void kernel_launch(void* const* d_in, const int* in_sizes, int n_in,
                              void* d_out, int out_size, void* d_ws, size_t ws_size,
                              hipStream_t stream){
  const float* x     = (const float*)d_in[0];
  const float* W_lin = (const float*)d_in[1];
  const float* b_lin = (const float*)d_in[2];
  const float* Ws    = (const float*)d_in[3];
  const float* W1    = (const float*)d_in[4];
  const float* b1    = (const float*)d_in[5];
  const float* ln_g  = (const float*)d_in[6];
  const float* ln_b  = (const float*)d_in[7];
  const float* W2    = (const float*)d_in[8];
  const float* b2    = (const float*)d_in[9];
  const int*   eidx  = (const int*)d_in[10];
  const int*   rowE  = eidx;
  const int*   colE  = eidx + N_EDGES;
  float* out = (float*)d_out;

  char* ws = (char*)d_ws;
  size_t o = 0;
  auto alloc = [&](size_t bytes)->char*{ char* p = ws + o; o = (o + bytes + 255) & ~(size_t)255; return p; };
  int*   row_fill= (int*)  alloc((size_t)N_NODES*4);
  int*   degcnt  = (int*)  alloc((size_t)N_NODES*4);   // becomes rdeg (float) after k_dinv
  float* dinv    = (float*)alloc((size_t)N_NODES*4);
  unsigned short* csr_col = (unsigned short*)alloc((size_t)N_NODES*CAP*2);
  unsigned* rstream = (unsigned*)alloc((size_t)NB*BCAP*4);
  unsigned short* cstream = (unsigned short*)alloc((size_t)NB*BCAP*2);
  int*   rcur    = (int*)  alloc((size_t)NB*CURPAD*4);
  int*   ccur    = (int*)  alloc((size_t)NB*CURPAD*4);
  __half* h0     = (__half*)alloc((size_t)(N_NODES+1)*64*2);
  __half* gA     = (__half*)alloc((size_t)(N_NODES+1)*64*2);
  __half* gB     = (__half*)alloc((size_t)(N_NODES+1)*64*2);
  float* rdeg    = (float*)degcnt;

  hipMemsetAsync(rcur, 0, (size_t)NB*CURPAD*4, stream);
  hipMemsetAsync(ccur, 0, (size_t)NB*CURPAD*4, stream);

  k_bin  <<<BIN_BLOCKS, 256, 0, stream>>>(rowE, colE, rstream, cstream, rcur, ccur);
  k_build<<<2*NB, 256, 0, stream>>>(rstream, cstream, rcur, ccur, row_fill, degcnt, csr_col);
  k_dinv <<<(N_NODES+255)/256, 256, 0, stream>>>(degcnt, dinv, gA, gB);

  k_lin0<<<N_NODES/16, 256, 0, stream>>>(x, W_lin, b_lin, dinv, h0, gA);

  const __half* gin = gA;
  __half* bufs[2] = {gB, gA};
  for(int L=0; L<8; L++){
    float beta = logf(0.5f/(float)(L+1) + 1.0f);
    __half* gout = bufs[L&1];
    k_layer<<<(N_NODES+15)/16, 256, 0, stream>>>(gin, h0, row_fill, csr_col, dinv,
                                                 Ws + (size_t)L*4096, beta, gout);
    gin = gout;
  }
  // final g is bufs[1] = gA (layer 7). Free: gB, h0 -> reuse for A,B.
  __half* Abuf = gB;
  __half* Bbuf = h0;
  k_ab<<<N_NODES/16, 256, 0, stream>>>(gA, rdeg, W1, Abuf, Bbuf);
  k_edge<<<EDGE_GRID, 256, 0, stream>>>(Abuf, Bbuf, rowE, colE, b1, ln_g, ln_b, W2, b2, out);
}